// Round 3
// baseline (9101.106 us; speedup 1.0000x reference)
//
#include <hip/hip_runtime.h>
#include <float.h>

// FPS: N=524288 pts, M=2048 selected (idx[0]=0), out = pos[idxs] (2048x3 f32).
// 512 cooperative blocks of exactly ONE wave each. Per iteration:
//   wave butterfly-reduce own 16 pts -> lane0 publishes tagged u64 slot ->
//   all 64 lanes poll 8 slots each (coalesced, in-flight together) ->
//   per-lane reduce + butterfly -> every wave knows global winner locally.
// No LDS, no __syncthreads, one LLC visibility hop per iteration.

#define NPTS     524288
#define MOUT     2048
#define NBLK     512                 // one wave per block
#define NTHR     64
#define GTHREADS (NBLK * NTHR)       // 32768
#define PPT      (NPTS / GTHREADS)   // 16
#define KPL      (NBLK / 64)         // slots per polling lane = 8
#define MASK51   ((1ull << 51) - 1)

// slot word: [tag:13][fbits:32][idx_inv:19]
// fbits = IEEE bits of min_d (>=0 so bit order == value order)
// idx_inv = (NPTS-1)-idx: among equal values the smaller idx wins the max
// => first-occurrence tie-break, matching jnp.argmax. Words are globally
// unique (point ownership partitioned) => winner lane identified by equality.

__global__ void __launch_bounds__(NTHR, 1) fps_kernel(
    const float* __restrict__ pos, float* __restrict__ out,
    unsigned long long* __restrict__ slots)
{
    const unsigned lane = threadIdx.x;
    const unsigned blk  = blockIdx.x;
    const unsigned g    = blk * NTHR + lane;

    float X[PPT], Y[PPT], Z[PPT], D[PPT];
#pragma unroll
    for (int p = 0; p < PPT; ++p) {
        const unsigned idx = g + (unsigned)p * GTHREADS;
        X[p] = pos[3u * idx + 0];
        Y[p] = pos[3u * idx + 1];
        Z[p] = pos[3u * idx + 2];
        D[p] = FLT_MAX;
    }

    float px = pos[0], py = pos[1], pz = pos[2];
    if (g == 0) { out[0] = px; out[1] = py; out[2] = pz; }

    for (int i = 1; i < MOUT; ++i) {
        // ---- distance update + per-thread argmax (exact fp32: no FMA,
        // ---- sum order (dx^2+dy^2)+dz^2; verified absmax==0 in R1/R2) ----
        float bv = -1.0f;
        unsigned bi = 0;
#pragma unroll
        for (int p = 0; p < PPT; ++p) {
            float dx = __fsub_rn(X[p], px);
            float dy = __fsub_rn(Y[p], py);
            float dz = __fsub_rn(Z[p], pz);
            float d  = __fadd_rn(__fadd_rn(__fmul_rn(dx, dx), __fmul_rn(dy, dy)),
                                 __fmul_rn(dz, dz));
            float m  = fminf(D[p], d);
            D[p] = m;
            if (m > bv) { bv = m; bi = g + (unsigned)p * GTHREADS; }
        }
        unsigned long long best =
            ((unsigned long long)__float_as_uint(bv) << 19) |
            (unsigned long long)((NPTS - 1u) - bi);

        // ---- butterfly: all lanes get the wave max ----
#pragma unroll
        for (int off = 32; off > 0; off >>= 1) {
            unsigned long long o = __shfl_xor(best, off, 64);
            if (o > best) best = o;
        }

        unsigned long long* buf = slots + (unsigned)(i & 1) * NBLK;
        if (lane == 0) {
            __hip_atomic_store(&buf[blk], ((unsigned long long)i << 51) | best,
                               __ATOMIC_RELAXED, __HIP_MEMORY_SCOPE_AGENT);
        }

        // ---- poll all 512 slots: lane reads slot lane+64k (coalesced 512B
        // ---- per k, all 8 loads in flight together => ~1 LLC latency) ----
        const unsigned long long tag = (unsigned long long)i;
        unsigned long long v[KPL];
        for (;;) {
            bool ok = true;
#pragma unroll
            for (int k = 0; k < KPL; ++k)
                v[k] = __hip_atomic_load(&buf[lane + (unsigned)k * 64u],
                                         __ATOMIC_RELAXED, __HIP_MEMORY_SCOPE_AGENT);
#pragma unroll
            for (int k = 0; k < KPL; ++k) ok &= ((v[k] >> 51) == tag);
            if (__all(ok)) break;
            __builtin_amdgcn_s_sleep(1);
        }

        // ---- per-lane reduce of its 8 candidates ----
        unsigned long long c = v[0] & MASK51;
#pragma unroll
        for (int k = 1; k < KPL; ++k) {
            unsigned long long w = v[k] & MASK51;
            if (w > c) c = w;
        }
        // prefetch this lane's candidate coords; load flies during butterfly
        unsigned cidx = (NPTS - 1u) - (unsigned)(c & 0x7FFFFull);
        float cx = pos[3u * cidx + 0];
        float cy = pos[3u * cidx + 1];
        float cz = pos[3u * cidx + 2];

        unsigned long long win = c;
#pragma unroll
        for (int off = 32; off > 0; off >>= 1) {
            unsigned long long o = __shfl_xor(win, off, 64);
            if (o > win) win = o;
        }
        // exactly one lane's candidate equals the winner (words unique)
        unsigned long long bal = __ballot(win == c);
        int src = __ffsll((unsigned long long)bal) - 1;
        px = __shfl(cx, src, 64);
        py = __shfl(cy, src, 64);
        pz = __shfl(cz, src, 64);

        if (blk == 0 && lane == 0) {
            out[3 * i + 0] = px; out[3 * i + 1] = py; out[3 * i + 2] = pz;
        }
    }
}

extern "C" void kernel_launch(void* const* d_in, const int* in_sizes, int n_in,
                              void* d_out, int out_size, void* d_ws, size_t ws_size,
                              hipStream_t stream) {
    const float* pos = (const float*)d_in[0];
    float* out = (float*)d_out;
    unsigned long long* slots = (unsigned long long*)d_ws;  // 2 x 512 x u64 = 8 KB
    // No memset: 0xAA poison decodes to tag 0x1555, never a real tag (1..2047);
    // monotone tags + 2-buffer rotation make stale words harmless.

    void* args[] = { (void*)&pos, (void*)&out, (void*)&slots };
    hipLaunchCooperativeKernel((void*)fps_kernel, dim3(NBLK), dim3(NTHR),
                               args, 0, stream);
}

// Round 4
// 4965.907 us; speedup vs baseline: 1.8327x; 1.8327x over previous
//
#include <hip/hip_runtime.h>
#include <float.h>

// FPS: N=524288 pts, M=2048 selected (idx[0]=0), out = pos[idxs] (2048x3 f32).
// 64 cooperative blocks x 512 threads (B=64 publishers, the R2 sweet spot).
// Per iteration: wave butterfly -> LDS (parity dbuf) -> every wave reduces the
// 8 wave-bests itself -> wave0 lane0 publishes tagged padded slot -> ALL waves
// poll (1 slot/lane) -> per-wave butterfly + prefetched-coord shuffle bcast.
// One __syncthreads per iteration, no post-exchange block sync.

#define NPTS     524288
#define MOUT     2048
#define NBLK     64
#define NTHR     512
#define NWAVE    (NTHR / 64)            // 8
#define GTHREADS (NBLK * NTHR)          // 32768
#define PPT      (NPTS / GTHREADS)      // 16
#define SLOT_STRIDE 8                   // u64 per slot -> 64 B line per publisher
#define MASK51   ((1ull << 51) - 1)

// slot word: [tag:13][fbits:32][idx_inv:19]
// fbits = IEEE bits of min_d (>=0 so bit order == value order)
// idx_inv = (NPTS-1)-idx: equal values -> smaller idx wins the max
// => first-occurrence tie-break == jnp.argmax (absmax 0.0 in R1-R3).
// Block bests are globally distinct (point ownership partitioned), so the
// winning lane after a reduce is identified by word equality.

__global__ void __launch_bounds__(NTHR, 1) fps_kernel(
    const float* __restrict__ pos, float* __restrict__ out,
    unsigned long long* __restrict__ slots)
{
    const unsigned tid  = threadIdx.x;
    const unsigned lane = tid & 63u;
    const unsigned wav  = tid >> 6;
    const unsigned blk  = blockIdx.x;
    const unsigned g    = blk * NTHR + tid;

    float X[PPT], Y[PPT], Z[PPT], D[PPT];
#pragma unroll
    for (int p = 0; p < PPT; ++p) {
        const unsigned idx = g + (unsigned)p * GTHREADS;
        X[p] = pos[3u * idx + 0];
        Y[p] = pos[3u * idx + 1];
        Z[p] = pos[3u * idx + 2];
        D[p] = FLT_MAX;
    }

    float px = pos[0], py = pos[1], pz = pos[2];
    if (g == 0) { out[0] = px; out[1] = py; out[2] = pz; }

    // Parity double-buffered cross-wave scratch: a fast wave at iter i+1
    // writes buffer (i+1)&1 while a slow wave may still read buffer i&1.
    __shared__ unsigned long long sred[2][NWAVE];

    for (int i = 1; i < MOUT; ++i) {
        // ---- distance update + per-thread argmax (exact fp32: no FMA,
        // ---- sum order (dx^2+dy^2)+dz^2; absmax==0 verified R1-R3) ----
        float bv = -1.0f;
        unsigned bi = 0;
#pragma unroll
        for (int p = 0; p < PPT; ++p) {
            float dx = __fsub_rn(X[p], px);
            float dy = __fsub_rn(Y[p], py);
            float dz = __fsub_rn(Z[p], pz);
            float d  = __fadd_rn(__fadd_rn(__fmul_rn(dx, dx), __fmul_rn(dy, dy)),
                                 __fmul_rn(dz, dz));
            float m  = fminf(D[p], d);
            D[p] = m;
            if (m > bv) { bv = m; bi = g + (unsigned)p * GTHREADS; }
        }
        unsigned long long best =
            ((unsigned long long)__float_as_uint(bv) << 19) |
            (unsigned long long)((NPTS - 1u) - bi);

        // ---- wave butterfly: all lanes get wave best ----
#pragma unroll
        for (int off = 32; off > 0; off >>= 1) {
            unsigned long long o = __shfl_xor(best, off, 64);
            if (o > best) best = o;
        }

        // ---- cross-wave reduce, symmetric: every wave computes block best ----
        unsigned long long* sb = sred[i & 1];
        if (lane == 0) sb[wav] = best;
        __syncthreads();
        unsigned long long b2 = sb[lane & (NWAVE - 1u)];
#pragma unroll
        for (int off = NWAVE / 2; off > 0; off >>= 1) {
            unsigned long long o = __shfl_xor(b2, off, 64);
            if (o > b2) b2 = o;
        }

        unsigned long long* buf = slots + (unsigned)(i & 1) * (NBLK * SLOT_STRIDE);
        if (tid == 0) {
            __hip_atomic_store(&buf[blk * SLOT_STRIDE],
                               ((unsigned long long)i << 51) | b2,
                               __ATOMIC_RELAXED, __HIP_MEMORY_SCOPE_AGENT);
        }

        // ---- every wave polls all 64 slots (1 padded slot per lane) ----
        const unsigned long long tag = (unsigned long long)i;
        unsigned long long s;
        do {
            s = __hip_atomic_load(&buf[lane * SLOT_STRIDE],
                                  __ATOMIC_RELAXED, __HIP_MEMORY_SCOPE_AGENT);
            if ((s >> 51) == tag) break;
            __builtin_amdgcn_s_sleep(1);
        } while (true);
        unsigned long long c = s & MASK51;

        // prefetch this lane's candidate coords; loads fly during butterfly
        unsigned cidx = (NPTS - 1u) - (unsigned)(c & 0x7FFFFull);
        float cx = pos[3u * cidx + 0];
        float cy = pos[3u * cidx + 1];
        float cz = pos[3u * cidx + 2];

        unsigned long long win = c;
#pragma unroll
        for (int off = 32; off > 0; off >>= 1) {
            unsigned long long o = __shfl_xor(win, off, 64);
            if (o > win) win = o;
        }
        unsigned long long bal = __ballot(win == c);   // exactly one lane matches
        int src = __ffsll(bal) - 1;
        px = __shfl(cx, src, 64);
        py = __shfl(cy, src, 64);
        pz = __shfl(cz, src, 64);

        if (blk == 0 && tid == 0) {
            out[3 * i + 0] = px; out[3 * i + 1] = py; out[3 * i + 2] = pz;
        }
        // no trailing __syncthreads: next iteration's pre-publish sync +
        // parity-dbuf LDS + tag monotonicity make the tail race-free.
    }
}

extern "C" void kernel_launch(void* const* d_in, const int* in_sizes, int n_in,
                              void* d_out, int out_size, void* d_ws, size_t ws_size,
                              hipStream_t stream) {
    const float* pos = (const float*)d_in[0];
    float* out = (float*)d_out;
    unsigned long long* slots = (unsigned long long*)d_ws;  // 2 x 64 x 64B = 8 KB
    // No memset: 0xAA poison decodes to tag 0x1555, never a real tag (1..2047);
    // monotone tags + 2-buffer rotation make stale words harmless.

    void* args[] = { (void*)&pos, (void*)&out, (void*)&slots };
    hipLaunchCooperativeKernel((void*)fps_kernel, dim3(NBLK), dim3(NTHR),
                               args, 0, stream);
}